// Round 13
// baseline (80.699 us; speedup 1.0000x reference)
//
#include <hip/hip_runtime.h>
#include <math.h>

typedef __attribute__((ext_vector_type(8))) __bf16 b16x8;
typedef __attribute__((ext_vector_type(4))) float f32x4;

__device__ __forceinline__ unsigned short f2bf(float x) {
    unsigned int v = __float_as_uint(x);
    v += 0x7fffu + ((v >> 16) & 1u);
    return (unsigned short)(v >> 16);
}

// 16-lane sum reduction entirely on the VALU via DPP (no LDS pipe).
__device__ __forceinline__ float red16(float x) {
    int v;
    v = __builtin_amdgcn_update_dpp(0, __float_as_int(x), 0xB1, 0xF, 0xF, true);
    x += __int_as_float(v);
    v = __builtin_amdgcn_update_dpp(0, __float_as_int(x), 0x4E, 0xF, 0xF, true);
    x += __int_as_float(v);
    v = __builtin_amdgcn_update_dpp(0, __float_as_int(x), 0x141, 0xF, 0xF, true);
    x += __int_as_float(v);
    v = __builtin_amdgcn_update_dpp(0, __float_as_int(x), 0x140, 0xF, 0xF, true);
    x += __int_as_float(v);
    return x;
}

// ---------------- repack kernel ---------------- (layout identical to R12)
// ws: [0, 819200): weights bf16, PER-WAVE-CONTIGUOUS, visit order:
//   slot l = kw*10 + ks*5 + kh   (conv tap = kh*5+kw, cin plane ks)
//   byte = l*16384 + wn*2048 + fr*1024 + lane*16
//   value = W[cin = ks*32 + (lane>>4)*8 + j][o = wn*32 + fr*16 + (lane&15)]
// [819200, 820224): bias_sum fp32 [256]
__global__ __launch_bounds__(256) void repack_w(
    const float* __restrict__ Wt, const float* __restrict__ bias,
    unsigned short* __restrict__ wsw, float* __restrict__ wsb) {
    int idx = blockIdx.x * 256 + threadIdx.x;
    if (idx < 409600) {
        int j    = idx & 7;
        int lane = (idx >> 3) & 63;
        int fr   = (idx >> 9) & 1;
        int wn   = (idx >> 10) & 7;
        int l    = idx >> 13;          // visit slot 0..49
        int kh   = l % 5;
        int ks   = (l / 5) & 1;
        int kw   = l / 10;
        int tap  = kh * 5 + kw;
        int col  = lane & 15;
        int cg   = lane >> 4;
        int o    = wn * 32 + fr * 16 + col;
        int cin  = ks * 32 + cg * 8 + j;
        int ic = cin >> 4, id = cin & 15;
        float w = Wt[((size_t)(ic * 256 + o) * 16 + id) * 25 + tap];
        wsw[idx] = f2bf(w);
    } else if (idx < 409856) {
        int o = idx - 409600;
        float s = 0.f;
        for (int ic = 0; ic < 4; ++ic) s += bias[ic * 256 + o];
        wsb[o] = s;
    }
}

// ---------------- main kernel ----------------
// OCCUPANCY KERNEL: 512 blocks x 1024 threads; tile = 16w x 8h px, all 256
// outs. Wave = 64 px (4 rows x 16 cols) x 32 outs (1 capsule) -> acc 32 regs;
// per slot: 4 ds_read_b128 A + 2 JIT global B + 8 MFMA. Total reg state <=64
// (forced by __launch_bounds__(1024,8)) -> 8 waves/SIMD, 2 blocks/CU =
// 32 waves/CU. Latency hiding via TLP; no window, no ping-pong, ZERO
// barriers after prologue. LDS = 30720 B (u halo 2 planes x 12x20).
__global__ __launch_bounds__(1024, 8) void caps_mfma(
    const float* __restrict__ u, const unsigned short* __restrict__ wsw,
    const float* __restrict__ wsb, float* __restrict__ out) {

    __shared__ __align__(16) unsigned short su_sh[15360];  // [plane2][hy12][hx20][cgp4][j8]

    const int tid  = threadIdx.x;
    const int lane = tid & 63;
    const int wid  = tid >> 6;      // 0..15
    const int pm   = wid >> 3;      // 0..1  pixel-row-group (4 rows each)
    const int wn   = wid & 7;       // 0..7  capsule (32 outs)
    const int col  = lane & 15;
    const int cg   = lane >> 4;     // 0..3  cin-group (x-group in C layout)

    const int bx  = blockIdx.x;     // 0..127: 16 tile-rows x 8 tile-cols
    const int b   = blockIdx.y;     // 0..3
    const int ty0 = (bx >> 3) * 8;
    const int tx0 = (bx & 7) * 16;

    f32x4 acc[4][2];
    #pragma unroll
    for (int f = 0; f < 4; ++f) {
        acc[f][0] = (f32x4)0.f;
        acc[f][1] = (f32x4)0.f;
    }

    // ---- stage u halo: 2 planes x 12 rows x 20 cols x 32 cin ----
    {
        const float* up = u + (size_t)b * 64 * 16384;
        #pragma unroll 1
        for (int i = tid; i < 15360; i += 1024) {
            int c2 = i / 240;                   // 0..63 = plane*32 + cin-local
            int s  = i - c2 * 240;
            int hy = s / 20, hx = s - hy * 20;  // halo coords 12x20
            int gy = ty0 - 2 + hy, gx = tx0 - 2 + hx;
            float v = 0.f;
            if ((unsigned)gy < 128u && (unsigned)gx < 128u)
                v = up[(size_t)c2 * 16384 + gy * 128 + gx];
            int c = c2 & 31;
            int cgp = (c >> 3) ^ ((hx >> 1) & 3);
            su_sh[(c2 >> 5) * 7680 + (hy * 20 + hx) * 32 + cgp * 8 + (c & 7)]
                = f2bf(v);
        }
    }
    __syncthreads();               // su_sh stable; no more barriers

    // per-wave weight pointer, walks 16384 B per slot in visit order
    const char* wp = ((const char*)wsw) + wn * 2048 + lane * 16;

    #pragma unroll
    for (int g = 0; g < 5; ++g) {                  // g == kw
        const int hx   = col + g;
        const int coff = hx * 32 + ((cg ^ ((hx >> 1) & 3)) * 8);
        #pragma unroll
        for (int ks = 0; ks < 2; ++ks) {
            const unsigned short* apb = su_sh + ks * 7680 + pm * 4 * 640 + coff;
            #pragma unroll
            for (int kh = 0; kh < 5; ++kh) {
                b16x8 bf0 = *reinterpret_cast<const b16x8*>(wp);
                b16x8 bf1 = *reinterpret_cast<const b16x8*>(wp + 1024);
                wp += 16384;
                b16x8 a0 = *reinterpret_cast<const b16x8*>(apb + (kh    ) * 640);
                b16x8 a1 = *reinterpret_cast<const b16x8*>(apb + (kh + 1) * 640);
                b16x8 a2 = *reinterpret_cast<const b16x8*>(apb + (kh + 2) * 640);
                b16x8 a3 = *reinterpret_cast<const b16x8*>(apb + (kh + 3) * 640);

                __builtin_amdgcn_s_setprio(1);
                acc[0][0] = __builtin_amdgcn_mfma_f32_16x16x32_bf16(
                    a0, bf0, acc[0][0], 0, 0, 0);
                acc[0][1] = __builtin_amdgcn_mfma_f32_16x16x32_bf16(
                    a0, bf1, acc[0][1], 0, 0, 0);
                acc[1][0] = __builtin_amdgcn_mfma_f32_16x16x32_bf16(
                    a1, bf0, acc[1][0], 0, 0, 0);
                acc[1][1] = __builtin_amdgcn_mfma_f32_16x16x32_bf16(
                    a1, bf1, acc[1][1], 0, 0, 0);
                acc[2][0] = __builtin_amdgcn_mfma_f32_16x16x32_bf16(
                    a2, bf0, acc[2][0], 0, 0, 0);
                acc[2][1] = __builtin_amdgcn_mfma_f32_16x16x32_bf16(
                    a2, bf1, acc[2][1], 0, 0, 0);
                acc[3][0] = __builtin_amdgcn_mfma_f32_16x16x32_bf16(
                    a3, bf0, acc[3][0], 0, 0, 0);
                acc[3][1] = __builtin_amdgcn_mfma_f32_16x16x32_bf16(
                    a3, bf1, acc[3][1], 0, 0, 0);
                __builtin_amdgcn_s_setprio(0);
            }
        }
    }

    // ---------------- epilogue: bias + r-scale + squash (DPP) + float4 store --
    float bsv0 = wsb[wn * 32 + col];
    float bsv1 = wsb[wn * 32 + 16 + col];

    const int xg = lane >> 4;   // x-group in C layout
    #pragma unroll
    for (int f = 0; f < 4; ++f) {
        int h = ty0 + pm * 4 + f;
        int rows = min(h + 2, 127) - max(h - 2, 0) + 1;
        float o0[4], o1[4];
        #pragma unroll
        for (int r = 0; r < 4; ++r) {
            int w = tx0 + xg * 4 + r;
            int colsv = min(w + 2, 127) - max(w - 2, 0) + 1;
            float rs = 1.0f / (8.0f * (float)(rows * colsv));
            float p0 = (acc[f][0][r] + bsv0) * rs;
            float p1 = (acc[f][1][r] + bsv1) * rs;
            o0[r] = p0; o1[r] = p1;
            float sv = red16(p0 * p0 + p1 * p1);
            float scale = sv / ((1.0f + sv) * sqrtf(sv + 1e-9f));
            o0[r] *= scale; o1[r] *= scale;
        }
        size_t base = ((size_t)((b * 8 + wn) * 32) + col) * 16384
                      + (size_t)h * 128 + tx0 + xg * 4;
        float4 v0 = make_float4(o0[0], o0[1], o0[2], o0[3]);
        float4 v1 = make_float4(o1[0], o1[1], o1[2], o1[3]);
        *reinterpret_cast<float4*>(out + base) = v0;
        *reinterpret_cast<float4*>(out + base + (size_t)16 * 16384) = v1;
    }
}

extern "C" void kernel_launch(void* const* d_in, const int* in_sizes, int n_in,
                              void* d_out, int out_size, void* d_ws, size_t ws_size,
                              hipStream_t stream) {
    const float* u    = (const float*)d_in[0];
    const float* Wt   = (const float*)d_in[1];
    const float* bias = (const float*)d_in[2];
    unsigned short* wsw = (unsigned short*)d_ws;
    float* wsb = (float*)((char*)d_ws + 819200);

    repack_w<<<1601, 256, 0, stream>>>(Wt, bias, wsw, wsb);
    caps_mfma<<<dim3(128, 4), 1024, 0, stream>>>(u, wsw, wsb, (float*)d_out);
}

// Round 15
// 59.099 us; speedup vs baseline: 1.3655x; 1.3655x over previous
//
#include <hip/hip_runtime.h>
#include <math.h>

typedef __attribute__((ext_vector_type(8))) __bf16 b16x8;
typedef __attribute__((ext_vector_type(4))) float f32x4;

__device__ __forceinline__ unsigned short f2bf(float x) {
    unsigned int v = __float_as_uint(x);
    v += 0x7fffu + ((v >> 16) & 1u);
    return (unsigned short)(v >> 16);
}

// ---------------- repack kernel ---------------- (layout identical to R12)
// ws: [0, 819200): weights bf16, PER-WAVE-CONTIGUOUS, visit order:
//   slot l = kw*10 + ks*5 + kh   (conv tap = kh*5+kw, cin plane ks)
//   byte = l*16384 + wn*2048 + fr*1024 + lane*16
//   value = W[cin = ks*32 + (lane>>4)*8 + j][o = wn*32 + fr*16 + (lane&15)]
// [819200, 820224): bias_sum fp32 [256]
__global__ __launch_bounds__(256) void repack_w(
    const float* __restrict__ Wt, const float* __restrict__ bias,
    unsigned short* __restrict__ wsw, float* __restrict__ wsb) {
    int idx = blockIdx.x * 256 + threadIdx.x;
    if (idx < 409600) {
        int j    = idx & 7;
        int lane = (idx >> 3) & 63;
        int fr   = (idx >> 9) & 1;
        int wn   = (idx >> 10) & 7;
        int l    = idx >> 13;          // visit slot 0..49
        int kh   = l % 5;
        int ks   = (l / 5) & 1;
        int kw   = l / 10;
        int tap  = kh * 5 + kw;
        int col  = lane & 15;
        int cg   = lane >> 4;
        int o    = wn * 32 + fr * 16 + col;
        int cin  = ks * 32 + cg * 8 + j;
        int ic = cin >> 4, id = cin & 15;
        float w = Wt[((size_t)(ic * 256 + o) * 16 + id) * 25 + tap];
        wsw[idx] = f2bf(w);
    } else if (idx < 409856) {
        int o = idx - 409600;
        float s = 0.f;
        for (int ic = 0; ic < 4; ++ic) s += bias[ic * 256 + o];
        wsb[o] = s;
    }
}

// ---------------- main kernel ----------------
// R12 structure (16 waves, 16x16 tile, wave = 128px x 32 out, zero barriers
// after prologue) with two changes:
//  1. SWAPPED MFMA operands: acc = mfma(W_frag, u_frag, acc). Fragment lane
//     layouts are symmetric (A: lane&15 = M, B: lane&15 = N), so the same
//     frags work; C becomes col(lane&15)=pixel-x, row=od. Squash over od is
//     then 8 in-lane values + shfl_xor(16)+shfl_xor(32), and stores are
//     contiguous per xg group.
//  2. DEEPER B prefetch: distance-2, 3 register buffers (compile-time %3
//     rotation, g-loop fully unrolled) to cover contended-L2 latency
//     (distance-1's ~300cyc cover < observed ~1000cyc stall budget).
__global__ __launch_bounds__(1024, 4) void caps_mfma(
    const float* __restrict__ u, const unsigned short* __restrict__ wsw,
    const float* __restrict__ wsb, float* __restrict__ out) {

    __shared__ __align__(16) unsigned short su_sh[25600];   // 2 planes x [hy20][hx20][cgp4][j8]

    const int tid  = threadIdx.x;
    const int lane = tid & 63;
    const int wid  = tid >> 6;      // 0..15
    const int wm   = wid >> 3;      // 0..1  pixel-row-group (8 rows each)
    const int wn   = wid & 7;       // 0..7  capsule (32 outs each)
    const int col  = lane & 15;
    const int xg   = lane >> 4;     // 0..3
    const int ybase = wm * 8;

    const int bx  = blockIdx.x;     // 0..63
    const int b   = blockIdx.y;     // 0..3
    const int ty0 = (bx >> 3) * 16;
    const int tx0 = (bx & 7) * 16;

    f32x4 acc[8][2];
    #pragma unroll
    for (int f = 0; f < 8; ++f) {
        acc[f][0] = (f32x4)0.f;
        acc[f][1] = (f32x4)0.f;
    }

    auto stage_u = [&](int half) {
        const float* up = u + ((size_t)b * 64 + half * 32) * 16384;
        unsigned short* dstp = su_sh + half * 12800;
        #pragma unroll 1
        for (int i = tid; i < 12800; i += 1024) {
            int c = i / 400;                    // cin local 0..31
            int s = i - c * 400;
            int hy = s / 20, hx = s - hy * 20;  // halo coords 0..19
            int gy = ty0 - 2 + hy, gx = tx0 - 2 + hx;
            float v = 0.f;
            if ((unsigned)gy < 128u && (unsigned)gx < 128u)
                v = up[(size_t)c * 16384 + gy * 128 + gx];
            int cgp = (c >> 3) ^ ((hx >> 1) & 3);
            dstp[(hy * 20 + hx) * 32 + cgp * 8 + (c & 7)] = f2bf(v);
        }
    };

    // per-wave weight base: slot stride 16384B, [wn]2048B, [fr]1024B, lane*16B
    const char* wp0 = ((const char*)wsw) + wn * 2048 + lane * 16;

    // B triple buffer (distance-2 prefetch), rotated at compile time
    b16x8 bf[3][2];
    #define LOADB(SLOT, BUF)                                                   \
        {                                                                      \
            const char* p_ = wp0 + (size_t)((SLOT) > 49 ? 49 : (SLOT)) * 16384;\
            bf[BUF][0] = *reinterpret_cast<const b16x8*>(p_);                  \
            bf[BUF][1] = *reinterpret_cast<const b16x8*>(p_ + 1024);           \
        }

    // prologue
    LOADB(0, 0)
    LOADB(1, 1)
    stage_u(0);
    stage_u(1);
    __syncthreads();               // su_sh stable from here on; no more barriers

    #pragma unroll
    for (int g = 0; g < 5; ++g) {                  // g == kw (fully unrolled)
        const int hx   = col + g;
        const int coff = hx * 32 + ((xg ^ ((hx >> 1) & 3)) * 8);
        #pragma unroll
        for (int ks = 0; ks < 2; ++ks) {
            const unsigned short* apb =
                su_sh + ks * 12800 + ybase * 640 + coff;

            // init circular A-window (u-frags): rows 0..7 relative to ybase
            b16x8 aw[8];
            #pragma unroll
            for (int i = 0; i < 8; ++i)
                aw[i] = *reinterpret_cast<const b16x8*>(apb + i * 640);

            #pragma unroll
            for (int kh = 0; kh < 5; ++kh) {
                const int l = g * 10 + ks * 5 + kh;     // compile-time

                LOADB(l + 2, (l + 2) % 3)               // distance-2 prefetch

                __builtin_amdgcn_s_setprio(1);
                #pragma unroll
                for (int f = 0; f < 8; ++f) {
                    // SWAPPED: A = weights (lane&15 = od), B = u (lane&15 = x)
                    acc[f][0] = __builtin_amdgcn_mfma_f32_16x16x32_bf16(
                        bf[l % 3][0], aw[(kh + f) & 7], acc[f][0], 0, 0, 0);
                    acc[f][1] = __builtin_amdgcn_mfma_f32_16x16x32_bf16(
                        bf[l % 3][1], aw[(kh + f) & 7], acc[f][1], 0, 0, 0);
                }
                __builtin_amdgcn_s_setprio(0);

                if (kh < 4)                             // slide AFTER cluster
                    aw[kh & 7] = *reinterpret_cast<const b16x8*>(
                        apb + (kh + 8) * 640);
            }
        }
    }
    #undef LOADB

    // ---- epilogue: bias + r-scale + squash (in-lane + 2 shfl) + stores ----
    // C layout after swap: value(y=ybase+f, x=tx0+col, od=fr*16+xg*4+r)
    float4 bb0 = *reinterpret_cast<const float4*>(wsb + wn * 32 + xg * 4);
    float4 bb1 = *reinterpret_cast<const float4*>(wsb + wn * 32 + 16 + xg * 4);

    const int x = tx0 + col;
    const int colsv = min(x + 2, 127) - max(x - 2, 0) + 1;
    float* pout = out + ((size_t)(b * 8 + wn) * 32 + xg * 4) * 16384 + x;

    #pragma unroll
    for (int f = 0; f < 8; ++f) {
        int h = ty0 + ybase + f;
        int rows = min(h + 2, 127) - max(h - 2, 0) + 1;
        float rs = 1.0f / (8.0f * (float)(rows * colsv));
        float p[8];
        float sq = 0.f;
        #pragma unroll
        for (int r = 0; r < 4; ++r) {
            float v0 = (acc[f][0][r] + bb0[r]) * rs;
            float v1 = (acc[f][1][r] + bb1[r]) * rs;
            p[r] = v0; p[4 + r] = v1;
            sq += v0 * v0;
            sq += v1 * v1;
        }
        sq += __shfl_xor(sq, 16);
        sq += __shfl_xor(sq, 32);
        float scale = sq / ((1.0f + sq) * sqrtf(sq + 1e-9f));
        float* ph = pout + (size_t)h * 128;
        #pragma unroll
        for (int r = 0; r < 4; ++r) {
            ph[(size_t)r * 16384]        = p[r] * scale;      // od = xg*4+r
            ph[(size_t)(16 + r) * 16384] = p[4 + r] * scale;  // od = 16+xg*4+r
        }
    }
}

extern "C" void kernel_launch(void* const* d_in, const int* in_sizes, int n_in,
                              void* d_out, int out_size, void* d_ws, size_t ws_size,
                              hipStream_t stream) {
    const float* u    = (const float*)d_in[0];
    const float* Wt   = (const float*)d_in[1];
    const float* bias = (const float*)d_in[2];
    unsigned short* wsw = (unsigned short*)d_ws;
    float* wsb = (float*)((char*)d_ws + 819200);

    repack_w<<<1601, 256, 0, stream>>>(Wt, bias, wsw, wsb);
    caps_mfma<<<dim3(64, 4), 1024, 0, stream>>>(u, wsw, wsb, (float*)d_out);
}